// Round 14
// baseline (14106.871 us; speedup 1.0000x reference)
//
#include <hip/hip_runtime.h>

// VQ-VAE quantize. Output BIT-EXACT vs numpy fp32 pipeline (proven R3-R13):
//   d_k = fl32( fl32(sumx + sume_k) - c_k ), c_k = sequential-k fp32 FMA of (2x).e,
//   idx = first-minimum argmin.
//
// R14: ONE MFMA sweep (sweep B deleted). During sweep A each lane tracks FOUR
// per-supertile minima ssmin[sti][st][r] (supertile = 8 lt = 8 k of this lane's
// c16 column) at the same 2 VALU/lt cost. After THR = gmin + W (verified W =
// SA*1.6e-5 + 4e-5), lanes flag cells with ssmin < THR(row) and append (row,
// kbase) cells; the exact rescore expands cells x8 k. Superset: k*'s cell has
// cellmin <= s~_{k*} < gmin+W -> flagged. SUMX precomputed per row (np order).
// R9's lesson kept: nothing on the MFMA critical path; R13's geometry kept
// (whole codebook in LDS, 16 waves, 8 row-groups x 2 k-halves, no sweep barriers).

#define N_ROWS   131072
#define NUM_EMB  1024
#define EMB_DIM  64
#define Q_ELEMS  8388608
#define THREADS  1024
#define ROWS_PB  512          // 8 row-groups x 64 rows; 2 k-halves
#define WCAP     1024         // cells (each cell = 8 k)

typedef short short8 __attribute__((ext_vector_type(8)));
typedef float f32x4  __attribute__((ext_vector_type(4)));

__device__ __forceinline__ unsigned short bf16_rne(float f) {
    unsigned u = __float_as_uint(f);
    u += 0x7fffu + ((u >> 16) & 1u);
    return (unsigned short)(u >> 16);
}

// monotone key for f32 (handles negatives): smaller float -> smaller key
__device__ __forceinline__ unsigned fkey(float d) {
    unsigned b = __float_as_uint(d);
    return b ^ (((unsigned)((int)b >> 31)) | 0x80000000u);
}

// numpy pairwise_sum (n=64) of fl32(a[i]*a[i]) — 8-accumulator order.
__device__ __forceinline__ float np_sq64(const float* a) {
    #pragma clang fp contract(off)
    float r0=a[0]*a[0],r1=a[1]*a[1],r2=a[2]*a[2],r3=a[3]*a[3];
    float r4=a[4]*a[4],r5=a[5]*a[5],r6=a[6]*a[6],r7=a[7]*a[7];
    #pragma unroll
    for (int i=8;i<64;i+=8){
        r0+=a[i+0]*a[i+0];r1+=a[i+1]*a[i+1];r2+=a[i+2]*a[i+2];r3+=a[i+3]*a[i+3];
        r4+=a[i+4]*a[i+4];r5+=a[i+5]*a[i+5];r6+=a[i+6]*a[i+6];r7+=a[i+7]*a[i+7];
    }
    return ((r0+r1)+(r2+r3))+((r4+r5)+(r6+r7));
}

// min over the 16 lanes of each DPP row (row_ror 1,2,4,8) — R7-R13-verified.
__device__ __forceinline__ float rotmin16(float v) {
    int x;
    x = __builtin_amdgcn_update_dpp(0, __float_as_int(v), 0x121, 0xf, 0xf, true);
    v = fminf(v, __int_as_float(x));
    x = __builtin_amdgcn_update_dpp(0, __float_as_int(v), 0x122, 0xf, 0xf, true);
    v = fminf(v, __int_as_float(x));
    x = __builtin_amdgcn_update_dpp(0, __float_as_int(v), 0x124, 0xf, 0xf, true);
    v = fminf(v, __int_as_float(x));
    x = __builtin_amdgcn_update_dpp(0, __float_as_int(v), 0x128, 0xf, 0xf, true);
    v = fminf(v, __int_as_float(x));
    return v;
}

// prep: sume (np order) + emb -> bf16, layout unit = chunk*1024 + gp*128 + krow
// (unit = 8 bf16 of dims gp*8..gp*8+7), chunk = k>>7, krow = k&127. Verified R8+.
__global__ __launch_bounds__(256) void vq_prep(const float* __restrict__ emb,
                                               float* __restrict__ sume,
                                               unsigned short* __restrict__ ehg) {
    int k = blockIdx.x * 256 + threadIdx.x;
    if (k < NUM_EMB) {
        sume[k] = np_sq64(emb + (k << 6));
        int c = k >> 7, krow = k & 127;
        #pragma unroll
        for (int gp = 0; gp < 8; ++gp) {
            short8 h;
            #pragma unroll
            for (int j = 0; j < 8; ++j)
                h[j] = (short)bf16_rne(emb[(k << 6) + gp*8 + j]);
            reinterpret_cast<short8*>(ehg)[c*1024 + gp*128 + krow] = h;
        }
    }
}

__global__ __launch_bounds__(THREADS, 4)
void vq_main(const float* __restrict__ x, const float* __restrict__ emb,
             const float* __restrict__ sume_g, const unsigned short* __restrict__ ehg,
             float* __restrict__ out_q, float* __restrict__ out_idx) {
    __shared__ int4     EH4[8192];        // 128 KB: ENTIRE bf16 codebook
    __shared__ float    SUME[NUM_EMB];    // 4 KB
    __shared__ float    LM[2][ROWS_PB];   // 4 KB per-k-half row minima
    __shared__ float    THR[ROWS_PB];     // 2 KB
    __shared__ float    SA[ROWS_PB];      // 2 KB
    __shared__ float    SUMX[ROWS_PB];    // 2 KB exact np sum(x^2) per row
    __shared__ int      WL[WCAP];         // 4 KB cell list (row<<10 | kbase)
    __shared__ unsigned DMIN[ROWS_PB];    // 2 KB
    __shared__ unsigned KMIN[ROWS_PB];    // 2 KB
    __shared__ int      SIDX[ROWS_PB];    // 2 KB
    __shared__ unsigned WCNT;

    const int t    = threadIdx.x;
    const int w    = t >> 6;         // wave 0..15
    const int w8   = w & 7;          // row-group: rows w8*64 .. w8*64+63
    const int half = w >> 3;         // k-half: k in [half*512, half*512+512)
    const int l    = t & 63;
    const int g    = l >> 4;         // K-dim quarter 0..3
    const int c16  = l & 15;
    const size_t blk_row0 = (size_t)blockIdx.x * ROWS_PB;

    // ---- stage whole codebook + sume ONCE (L2-resident source).
    const int4* eg4 = reinterpret_cast<const int4*>(ehg);
    #pragma unroll
    for (int i = 0; i < 8; ++i) EH4[t + i*THREADS] = eg4[t + i*THREADS];
    SUME[t] = sume_g[t];
    if (t < ROWS_PB) {
        DMIN[t] = 0xFFFFFFFFu; KMIN[t] = 0xFFFFFFFFu;
        SUMX[t] = np_sq64(x + (blk_row0 + (size_t)t) * EMB_DIM);  // exact np order
    }
    if (t == 0) WCNT = 0u;

    // ---- x-fragments: 4 strips x 16 rows (A[m][kd], m = lane&15 = x-row;
    // kd = 8*(lane>>4)+j — R8-R13-verified). float4 loads. 2.0 folded.
    short8 ah[4][2];
    #pragma unroll
    for (int st = 0; st < 4; ++st) {
        const float4* xq = reinterpret_cast<const float4*>(
            x + (blk_row0 + (size_t)(w8*64 + st*16 + c16)) * EMB_DIM);
        float sabs = 0.f;
        #pragma unroll
        for (int hf = 0; hf < 2; ++hf) {
            float4 u0 = xq[hf*8 + g*2 + 0];
            float4 u1 = xq[hf*8 + g*2 + 1];
            float vv[8] = {u0.x,u0.y,u0.z,u0.w,u1.x,u1.y,u1.z,u1.w};
            #pragma unroll
            for (int j = 0; j < 8; ++j) {
                float v = 2.0f * vv[j];
                sabs += fabsf(v);
                ah[st][hf][j] = (short)bf16_rne(v);
            }
        }
        sabs += __shfl_xor(sabs, 16);
        sabs += __shfl_xor(sabs, 32);
        if (g == 0 && half == 0) SA[w8*64 + st*16 + c16] = sabs;
    }
    __syncthreads();    // EH/SUME/SA/SUMX ready

    // ---- sweep A (the ONLY sweep): 32 k-tiles x 4 strips, reg-only MFMA,
    // NO barriers. Per-supertile minima (sti = 8 lt), statically indexed.
    float ssmin[4][4][4];
    #pragma unroll
    for (int sti = 0; sti < 4; ++sti)
        #pragma unroll
        for (int st = 0; st < 4; ++st)
            #pragma unroll
            for (int r = 0; r < 4; ++r) ssmin[sti][st][r] = 3.4e38f;

    const short8* EHs = reinterpret_cast<const short8*>(EH4);
    #pragma unroll
    for (int sti = 0; sti < 4; ++sti) {
        #pragma unroll 4
        for (int j = 0; j < 8; ++j) {
            const int ub = (half*4 + sti)*1024 + j*16 + c16;  // chunk/krow decode
            short8 bh0 = EHs[ub + (g    )*128];
            short8 bh1 = EHs[ub + (g + 4)*128];
            float scol = SUME[(half*32 + sti*8 + j)*16 + c16];
            #pragma unroll
            for (int st = 0; st < 4; ++st) {
                f32x4 a = {0.f,0.f,0.f,0.f};
                a = __builtin_amdgcn_mfma_f32_16x16x32_bf16(ah[st][0], bh0, a, 0,0,0);
                a = __builtin_amdgcn_mfma_f32_16x16x32_bf16(ah[st][1], bh1, a, 0,0,0);
                #pragma unroll
                for (int r = 0; r < 4; ++r)
                    ssmin[sti][st][r] = fminf(ssmin[sti][st][r], scol - a[r]);
            }
        }
    }

    // D-row = st*16 + 4*g + r, D-col = c16 = k (verified); min over cols via DPP.
    #pragma unroll
    for (int st = 0; st < 4; ++st) {
        #pragma unroll
        for (int r = 0; r < 4; ++r) {
            float m4 = fminf(fminf(ssmin[0][st][r], ssmin[1][st][r]),
                             fminf(ssmin[2][st][r], ssmin[3][st][r]));
            float v = rotmin16(m4);
            if (c16 == 0) LM[half][w8*64 + st*16 + 4*g + r] = v;
        }
    }
    __syncthreads();
    if (t < ROWS_PB) {
        float bm = fminf(LM[0][t], LM[1][t]);
        // W = SA*2^-16 (two-sided bf16 product err, conservative) + grid/acc slack
        THR[t] = bm + (SA[t] * 1.6e-5f + 4.0e-5f);
    }
    __syncthreads();

    // ---- flag & append cells: lane's cell = 8 k {(half*32+sti*8+j)*16+c16}.
    // Superset guarantee: k*'s cell has cellmin <= s~_{k*} < gmin+W = THR.
    #pragma unroll
    for (int st = 0; st < 4; ++st) {
        #pragma unroll
        for (int r = 0; r < 4; ++r) {
            const float th = THR[w8*64 + st*16 + 4*g + r];
            const int   rb = (w8*64 + st*16 + 4*g + r) << 10;
            #pragma unroll
            for (int sti = 0; sti < 4; ++sti) {
                if (ssmin[sti][st][r] < th) {
                    unsigned q = atomicAdd(&WCNT, 1u);
                    if (q < WCAP) WL[q] = rb | (half*512 + sti*128 + c16);
                }
            }
        }
    }
    __syncthreads();

    const unsigned wc = WCNT;                      // uniform (post-barrier)
    float* WLD = reinterpret_cast<float*>(EH4);    // EH dead: alias rescore scratch

    if (wc <= WCAP) {
        // lane-parallel BIT-EXACT rescore of cells x 8 k (~5.7K tasks expected).
        const unsigned nt = wc * 8u;
        for (unsigned tq = t; tq < nt; tq += THREADS) {
            int cell = WL[tq >> 3];
            int row  = cell >> 10;
            int kk   = (cell & 1023) + (int)(tq & 7u) * 16;
            const float* xr = x + (blk_row0 + (size_t)row) * EMB_DIM;
            const float* er = emb + (kk << 6);
            float cc = 0.f;
            #pragma unroll 8
            for (int i = 0; i < EMB_DIM; ++i)
                cc = fmaf(2.0f * xr[i], er[i], cc);   // sgemm sequential-k order
            float d;
            {
                #pragma clang fp contract(off)
                d = (SUMX[row] + SUME[kk]) - cc;      // fl32 grid @ ~64
            }
            WLD[tq] = d;
            atomicMin(&DMIN[row], fkey(d));
        }
        __syncthreads();
        for (unsigned tq = t; tq < nt; tq += THREADS) {
            int cell = WL[tq >> 3];
            int row  = cell >> 10;
            int kk   = (cell & 1023) + (int)(tq & 7u) * 16;
            if (fkey(WLD[tq]) == DMIN[row])
                atomicMin(&KMIN[row], (unsigned)kk);  // ties -> smallest k = first-min
        }
        __syncthreads();
        if (t < ROWS_PB) {
            int bk = (int)KMIN[t];
            SIDX[t] = bk;
            out_idx[blk_row0 + t] = (float)bk;
        }
    } else {
        // cold exact fallback (cell-list overflow; never on sane data).
        if (t < ROWS_PB) {
            const float* xr = x + (blk_row0 + (size_t)t) * EMB_DIM;
            float sumx = SUMX[t];
            volatile const float* xv = xr;
            float bm = 3.4e38f; int bb = 0;
            for (int kk = 0; kk < NUM_EMB; ++kk) {
                const float* er = emb + (kk << 6);
                float cc = 0.f;
                for (int i = 0; i < EMB_DIM; ++i)
                    cc = fmaf(2.0f * xv[i], er[i], cc);
                {
                    #pragma clang fp contract(off)
                    float d = (sumx + SUME[kk]) - cc;
                    if (d < bm) { bm = d; bb = kk; }
                }
            }
            SIDX[t] = bb;
            out_idx[blk_row0 + t] = (float)bb;
        }
    }
    __syncthreads();

    // ---- coalesced gather: quantized[row] = emb[idx[row]]
    const float4* emb4 = reinterpret_cast<const float4*>(emb);
    float4* q4 = reinterpret_cast<float4*>(out_q + blk_row0 * EMB_DIM);
    #pragma unroll
    for (int i = 0; i < 8; ++i) {
        int e4 = t + i * THREADS;     // 8192 float4 per block
        int rr = e4 >> 4, cc2 = e4 & 15;
        q4[e4] = emb4[SIDX[rr]*16 + cc2];
    }
}

extern "C" void kernel_launch(void* const* d_in, const int* in_sizes, int n_in,
                              void* d_out, int out_size, void* d_ws, size_t ws_size,
                              hipStream_t stream) {
    const float* x   = (const float*)d_in[0];
    const float* emb = (const float*)d_in[1];
    float* out_q   = (float*)d_out;
    float* out_idx = out_q + Q_ELEMS;
    float*          sume = (float*)d_ws;                          // 4 KB
    unsigned short* ehg  = (unsigned short*)((char*)d_ws + 4096); // 128 KB bf16 emb

    vq_prep<<<dim3(NUM_EMB / 256), dim3(256), 0, stream>>>(emb, sume, ehg);
    vq_main<<<dim3(N_ROWS / ROWS_PB), dim3(THREADS), 0, stream>>>(x, emb, sume, ehg,
                                                                  out_q, out_idx);
}

// Round 15
// 331.751 us; speedup vs baseline: 42.5225x; 42.5225x over previous
//
#include <hip/hip_runtime.h>

// VQ-VAE quantize. Output BIT-EXACT vs numpy fp32 pipeline (proven R3-R14):
//   d_k = fl32( fl32(sumx + sume_k) - c_k ), c_k = sequential-k fp32 FMA of (2x).e,
//   idx = first-minimum argmin.
//
// R15 = R14 (single MFMA sweep + per-supertile minima + cell rescore) with the
// two R14 failures fixed:
//  1) WCAP 1024 -> 8192 (WL aliased into EH4, dead after the sweep): R14's
//     ~1000 cells/block overflowed half the blocks into the 14ms fallback.
//  2) VGPR spill: ssmin[4][4][4] (64 regs) + launch_bounds(1024,4) gave a
//     64-VGPR cap (CUDA-style blocks/CU semantics) -> scratch in the hot loop.
//     Now ssmin[2][4][4] (32 regs, 16-k cells) + launch_bounds(1024,1) (cap 128).
//  3) WLD deleted: rescore recomputes d bit-identically in both passes
//     (sequential-FMA chain value is schedule-invariant).

#define N_ROWS   131072
#define NUM_EMB  1024
#define EMB_DIM  64
#define Q_ELEMS  8388608
#define THREADS  1024
#define ROWS_PB  512          // 8 row-groups x 64 rows; 2 k-halves
#define WCAP     8192         // cells (each cell = 16 k); lives in dead EH4

typedef short short8 __attribute__((ext_vector_type(8)));
typedef float f32x4  __attribute__((ext_vector_type(4)));

__device__ __forceinline__ unsigned short bf16_rne(float f) {
    unsigned u = __float_as_uint(f);
    u += 0x7fffu + ((u >> 16) & 1u);
    return (unsigned short)(u >> 16);
}

// monotone key for f32 (handles negatives): smaller float -> smaller key
__device__ __forceinline__ unsigned fkey(float d) {
    unsigned b = __float_as_uint(d);
    return b ^ (((unsigned)((int)b >> 31)) | 0x80000000u);
}

// numpy pairwise_sum (n=64) of fl32(a[i]*a[i]) — 8-accumulator order.
__device__ __forceinline__ float np_sq64(const float* a) {
    #pragma clang fp contract(off)
    float r0=a[0]*a[0],r1=a[1]*a[1],r2=a[2]*a[2],r3=a[3]*a[3];
    float r4=a[4]*a[4],r5=a[5]*a[5],r6=a[6]*a[6],r7=a[7]*a[7];
    #pragma unroll
    for (int i=8;i<64;i+=8){
        r0+=a[i+0]*a[i+0];r1+=a[i+1]*a[i+1];r2+=a[i+2]*a[i+2];r3+=a[i+3]*a[i+3];
        r4+=a[i+4]*a[i+4];r5+=a[i+5]*a[i+5];r6+=a[i+6]*a[i+6];r7+=a[i+7]*a[i+7];
    }
    return ((r0+r1)+(r2+r3))+((r4+r5)+(r6+r7));
}

// exact fp32 distance on the reference grid (identical in both rescore passes:
// sequential-FMA chain value is schedule-invariant; no contraction on the tail).
__device__ __forceinline__ float exact_d(const float* __restrict__ xr,
                                         const float* __restrict__ er,
                                         float sumx, float sume) {
    float cc = 0.f;
    #pragma unroll 8
    for (int i = 0; i < EMB_DIM; ++i)
        cc = fmaf(2.0f * xr[i], er[i], cc);   // sgemm sequential-k order
    {
        #pragma clang fp contract(off)
        float d = (sumx + sume) - cc;         // fl32 grid @ ~64
        return d;
    }
}

// min over the 16 lanes of each DPP row (row_ror 1,2,4,8) — R7-R14-verified.
__device__ __forceinline__ float rotmin16(float v) {
    int x;
    x = __builtin_amdgcn_update_dpp(0, __float_as_int(v), 0x121, 0xf, 0xf, true);
    v = fminf(v, __int_as_float(x));
    x = __builtin_amdgcn_update_dpp(0, __float_as_int(v), 0x122, 0xf, 0xf, true);
    v = fminf(v, __int_as_float(x));
    x = __builtin_amdgcn_update_dpp(0, __float_as_int(v), 0x124, 0xf, 0xf, true);
    v = fminf(v, __int_as_float(x));
    x = __builtin_amdgcn_update_dpp(0, __float_as_int(v), 0x128, 0xf, 0xf, true);
    v = fminf(v, __int_as_float(x));
    return v;
}

// prep: sume (np order) + emb -> bf16, layout unit = chunk*1024 + gp*128 + krow
// (unit = 8 bf16 of dims gp*8..gp*8+7), chunk = k>>7, krow = k&127. Verified R8+.
__global__ __launch_bounds__(256) void vq_prep(const float* __restrict__ emb,
                                               float* __restrict__ sume,
                                               unsigned short* __restrict__ ehg) {
    int k = blockIdx.x * 256 + threadIdx.x;
    if (k < NUM_EMB) {
        sume[k] = np_sq64(emb + (k << 6));
        int c = k >> 7, krow = k & 127;
        #pragma unroll
        for (int gp = 0; gp < 8; ++gp) {
            short8 h;
            #pragma unroll
            for (int j = 0; j < 8; ++j)
                h[j] = (short)bf16_rne(emb[(k << 6) + gp*8 + j]);
            reinterpret_cast<short8*>(ehg)[c*1024 + gp*128 + krow] = h;
        }
    }
}

__global__ __launch_bounds__(THREADS, 1)
void vq_main(const float* __restrict__ x, const float* __restrict__ emb,
             const float* __restrict__ sume_g, const unsigned short* __restrict__ ehg,
             float* __restrict__ out_q, float* __restrict__ out_idx) {
    __shared__ int4     EH4[8192];        // 128 KB codebook; WL aliases it later
    __shared__ float    SUME[NUM_EMB];    // 4 KB
    __shared__ float    LM[2][ROWS_PB];   // 4 KB per-k-half row minima
    __shared__ float    THR[ROWS_PB];     // 2 KB
    __shared__ float    SA[ROWS_PB];      // 2 KB
    __shared__ float    SUMX[ROWS_PB];    // 2 KB exact np sum(x^2) per row
    __shared__ unsigned DMIN[ROWS_PB];    // 2 KB
    __shared__ unsigned KMIN[ROWS_PB];    // 2 KB
    __shared__ int      SIDX[ROWS_PB];    // 2 KB
    __shared__ unsigned WCNT;

    const int t    = threadIdx.x;
    const int w    = t >> 6;         // wave 0..15
    const int w8   = w & 7;          // row-group: rows w8*64 .. w8*64+63
    const int half = w >> 3;         // k-half: k in [half*512, half*512+512)
    const int l    = t & 63;
    const int g    = l >> 4;         // group 0..3
    const int c16  = l & 15;
    const size_t blk_row0 = (size_t)blockIdx.x * ROWS_PB;

    // ---- stage whole codebook + sume ONCE (L2-resident source).
    const int4* eg4 = reinterpret_cast<const int4*>(ehg);
    #pragma unroll
    for (int i = 0; i < 8; ++i) EH4[t + i*THREADS] = eg4[t + i*THREADS];
    SUME[t] = sume_g[t];
    if (t < ROWS_PB) {
        DMIN[t] = 0xFFFFFFFFu; KMIN[t] = 0xFFFFFFFFu;
        SUMX[t] = np_sq64(x + (blk_row0 + (size_t)t) * EMB_DIM);  // exact np order
    }
    if (t == 0) WCNT = 0u;

    // ---- x-fragments: 4 strips x 16 rows (A[m][kd], m = lane&15 = x-row;
    // kd = 8*(lane>>4)+j — R8-R14-verified). float4 loads. 2.0 folded.
    short8 ah[4][2];
    #pragma unroll
    for (int st = 0; st < 4; ++st) {
        const float4* xq = reinterpret_cast<const float4*>(
            x + (blk_row0 + (size_t)(w8*64 + st*16 + c16)) * EMB_DIM);
        float sabs = 0.f;
        #pragma unroll
        for (int hf = 0; hf < 2; ++hf) {
            float4 u0 = xq[hf*8 + g*2 + 0];
            float4 u1 = xq[hf*8 + g*2 + 1];
            float vv[8] = {u0.x,u0.y,u0.z,u0.w,u1.x,u1.y,u1.z,u1.w};
            #pragma unroll
            for (int j = 0; j < 8; ++j) {
                float v = 2.0f * vv[j];
                sabs += fabsf(v);
                ah[st][hf][j] = (short)bf16_rne(v);
            }
        }
        sabs += __shfl_xor(sabs, 16);
        sabs += __shfl_xor(sabs, 32);
        if (g == 0 && half == 0) SA[w8*64 + st*16 + c16] = sabs;
    }
    __syncthreads();    // EH/SUME/SA/SUMX ready

    // ---- sweep A (the ONLY sweep): 32 k-tiles x 4 strips, reg-only MFMA,
    // NO barriers. Per-supertile minima (sti = 16 lt = 16 k), static indexing.
    float ssmin[2][4][4];
    #pragma unroll
    for (int sti = 0; sti < 2; ++sti)
        #pragma unroll
        for (int st = 0; st < 4; ++st)
            #pragma unroll
            for (int r = 0; r < 4; ++r) ssmin[sti][st][r] = 3.4e38f;

    const short8* EHs = reinterpret_cast<const short8*>(EH4);
    #pragma unroll
    for (int sti = 0; sti < 2; ++sti) {
        #pragma unroll 4
        for (int j = 0; j < 16; ++j) {
            const int ltg = half*32 + sti*16 + j;
            const int ub  = (ltg >> 3)*1024 + (ltg & 7)*16 + c16;  // chunk/krow
            short8 bh0 = EHs[ub + (g    )*128];
            short8 bh1 = EHs[ub + (g + 4)*128];
            float scol = SUME[ltg*16 + c16];
            #pragma unroll
            for (int st = 0; st < 4; ++st) {
                f32x4 a = {0.f,0.f,0.f,0.f};
                a = __builtin_amdgcn_mfma_f32_16x16x32_bf16(ah[st][0], bh0, a, 0,0,0);
                a = __builtin_amdgcn_mfma_f32_16x16x32_bf16(ah[st][1], bh1, a, 0,0,0);
                #pragma unroll
                for (int r = 0; r < 4; ++r)
                    ssmin[sti][st][r] = fminf(ssmin[sti][st][r], scol - a[r]);
            }
        }
    }

    // D-row = st*16 + 4*g + r, D-col = c16 (k-col) — verified; min via DPP.
    #pragma unroll
    for (int st = 0; st < 4; ++st) {
        #pragma unroll
        for (int r = 0; r < 4; ++r) {
            float v = rotmin16(fminf(ssmin[0][st][r], ssmin[1][st][r]));
            if (c16 == 0) LM[half][w8*64 + st*16 + 4*g + r] = v;
        }
    }
    __syncthreads();
    if (t < ROWS_PB) {
        float bm = fminf(LM[0][t], LM[1][t]);
        // W = SA*2^-16 (two-sided bf16 product err, conservative) + grid/acc slack
        THR[t] = bm + (SA[t] * 1.6e-5f + 4.0e-5f);
    }
    __syncthreads();

    // ---- flag & append cells into WL (aliased onto dead EH4).
    // Cell = 16 k: {half*512 + sti*256 + j*16 + c16, j=0..15}.
    // Superset: k*'s cell has cellmin <= s~_{k*} < gmin+W = THR.
    int* WL = reinterpret_cast<int*>(EH4);
    #pragma unroll
    for (int st = 0; st < 4; ++st) {
        #pragma unroll
        for (int r = 0; r < 4; ++r) {
            const float th = THR[w8*64 + st*16 + 4*g + r];
            const int   rb = (w8*64 + st*16 + 4*g + r) << 10;
            #pragma unroll
            for (int sti = 0; sti < 2; ++sti) {
                if (ssmin[sti][st][r] < th) {
                    unsigned q = atomicAdd(&WCNT, 1u);
                    if (q < WCAP) WL[q] = rb | (half*512 + sti*256 + c16);
                }
            }
        }
    }
    __syncthreads();

    const unsigned wc = WCNT;                      // uniform (post-barrier)

    if (wc <= WCAP) {
        // lane-parallel BIT-EXACT rescore of cells x 16 k (~16K tasks expected).
        // Pass 1: d -> DMIN. Pass 2: recompute d (bit-identical), match -> KMIN.
        const unsigned nt = wc * 16u;
        for (unsigned tq = t; tq < nt; tq += THREADS) {
            int cell = WL[tq >> 4];
            int row  = cell >> 10;
            int kk   = (cell & 1023) + (int)(tq & 15u) * 16;
            float d  = exact_d(x + (blk_row0 + (size_t)row) * EMB_DIM,
                               emb + (kk << 6), SUMX[row], SUME[kk]);
            atomicMin(&DMIN[row], fkey(d));
        }
        __syncthreads();
        for (unsigned tq = t; tq < nt; tq += THREADS) {
            int cell = WL[tq >> 4];
            int row  = cell >> 10;
            int kk   = (cell & 1023) + (int)(tq & 15u) * 16;
            float d  = exact_d(x + (blk_row0 + (size_t)row) * EMB_DIM,
                               emb + (kk << 6), SUMX[row], SUME[kk]);
            if (fkey(d) == DMIN[row])
                atomicMin(&KMIN[row], (unsigned)kk);  // ties -> smallest k = first-min
        }
        __syncthreads();
        if (t < ROWS_PB) {
            int bk = (int)KMIN[t];
            SIDX[t] = bk;
            out_idx[blk_row0 + t] = (float)bk;
        }
    } else {
        // cold exact fallback (cell-list overflow; unreachable at WCAP=8192).
        if (t < ROWS_PB) {
            const float* xr = x + (blk_row0 + (size_t)t) * EMB_DIM;
            float sumx = SUMX[t];
            volatile const float* xv = xr;
            float bm = 3.4e38f; int bb = 0;
            for (int kk = 0; kk < NUM_EMB; ++kk) {
                const float* er = emb + (kk << 6);
                float cc = 0.f;
                for (int i = 0; i < EMB_DIM; ++i)
                    cc = fmaf(2.0f * xv[i], er[i], cc);
                {
                    #pragma clang fp contract(off)
                    float d = (sumx + SUME[kk]) - cc;
                    if (d < bm) { bm = d; bb = kk; }
                }
            }
            SIDX[t] = bb;
            out_idx[blk_row0 + t] = (float)bb;
        }
    }
    __syncthreads();

    // ---- coalesced gather: quantized[row] = emb[idx[row]]
    const float4* emb4 = reinterpret_cast<const float4*>(emb);
    float4* q4 = reinterpret_cast<float4*>(out_q + blk_row0 * EMB_DIM);
    #pragma unroll
    for (int i = 0; i < 8; ++i) {
        int e4 = t + i * THREADS;     // 8192 float4 per block
        int rr = e4 >> 4, cc2 = e4 & 15;
        q4[e4] = emb4[SIDX[rr]*16 + cc2];
    }
}

extern "C" void kernel_launch(void* const* d_in, const int* in_sizes, int n_in,
                              void* d_out, int out_size, void* d_ws, size_t ws_size,
                              hipStream_t stream) {
    const float* x   = (const float*)d_in[0];
    const float* emb = (const float*)d_in[1];
    float* out_q   = (float*)d_out;
    float* out_idx = out_q + Q_ELEMS;
    float*          sume = (float*)d_ws;                          // 4 KB
    unsigned short* ehg  = (unsigned short*)((char*)d_ws + 4096); // 128 KB bf16 emb

    vq_prep<<<dim3(NUM_EMB / 256), dim3(256), 0, stream>>>(emb, sume, ehg);
    vq_main<<<dim3(N_ROWS / ROWS_PB), dim3(THREADS), 0, stream>>>(x, emb, sume, ehg,
                                                                  out_q, out_idx);
}